// Round 5
// baseline (147.216 us; speedup 1.0000x reference)
//
#include <hip/hip_runtime.h>
#include <stdint.h>
#include <math.h>

typedef unsigned long long u64;

#define KOUT    512
#define CHUNK   4096    // rows per filter block
#define FTH     256     // filter threads
#define CAP     2048    // per-batch candidate capacity
#define KEEPALL 768     // L <= this: keep every row, no filtering
#define MTH     512     // merge threads
#define RNB     4096    // fallback bins
#define RBUF    2560    // fallback collect buffer

// Monotone float->uint32 map (order-preserving), exactly invertible.
__device__ __forceinline__ uint32_t fmap(float f) {
    uint32_t u = __float_as_uint(f);
    return (u & 0x80000000u) ? ~u : (u | 0x80000000u);
}
__device__ __forceinline__ float funmap(uint32_t m) {
    uint32_t u = (m & 0x80000000u) ? (m & 0x7fffffffu) : ~m;
    return __uint_as_float(u);
}

// Acklam inverse normal CDF (float); ~1e-3 accuracy, verified exactly downstream.
__device__ __forceinline__ float norm_icdf(float p) {
    const float a1=-3.969683028665376e+01f,a2= 2.209460984245205e+02f,a3=-2.759285104469687e+02f,
                a4= 1.383577518672690e+02f,a5=-3.066479806614716e+01f,a6= 2.506628277459239e+00f;
    const float b1=-5.447609879822406e+01f,b2= 1.615858368580409e+02f,b3=-1.556989798598866e+02f,
                b4= 6.680131188771972e+01f,b5=-1.328068155288572e+01f;
    const float c1=-7.784894002430293e-03f,c2=-3.223964580411365e-01f,c3=-2.400758277161838e+00f,
                c4=-2.549732539343734e+00f,c5= 4.374664141464968e+00f,c6= 2.938163982698783e+00f;
    const float d1= 7.784695709041462e-03f,d2= 3.224671290700398e-01f,d3= 2.445134137142996e+00f,
                d4= 3.754408661907416e+00f;
    if (p < 0.02425f) {
        float q = sqrtf(-2.0f * logf(p));
        return (((((c1*q+c2)*q+c3)*q+c4)*q+c5)*q+c6) / ((((d1*q+d2)*q+d3)*q+d4)*q+1.0f);
    } else if (p <= 0.97575f) {
        float q = p - 0.5f, r = q*q;
        return (((((a1*r+a2)*r+a3)*r+a4)*r+a5)*r+a6)*q / (((((b1*r+b2)*r+b3)*r+b4)*r+b5)*r+1.0f);
    } else {
        float q = sqrtf(-2.0f * logf(1.0f - p));
        return -(((((c1*q+c2)*q+c3)*q+c4)*q+c5)*q+c6) / ((((d1*q+d2)*q+d3)*q+d4)*q+1.0f);
    }
}

__device__ __forceinline__ void append_pair(
    u64* myc, uint32_t* gc, int lane, bool k0, bool k1,
    float x0, float y0, float x1, float y1)
{
    u64 m0 = __ballot(k0);
    u64 m1 = __ballot(k1);
    if (m0 | m1) {
        int c0 = __popcll(m0);
        int ct = c0 + __popcll(m1);
        uint32_t base = 0;
        if (lane == 0) base = atomicAdd(gc, (uint32_t)ct);
        base = __shfl(base, 0, 64);
        u64 lt = ((u64)1 << lane) - 1ull;
        if (k0) {
            uint32_t s = base + (uint32_t)__popcll(m0 & lt);
            if (s < CAP) myc[s] = ((u64)fmap(x0) << 32) | fmap(y0);
        }
        if (k1) {
            uint32_t s = base + (uint32_t)(c0 + __popcll(m1 & lt));
            if (s < CAP) myc[s] = ((u64)fmap(x1) << 32) | fmap(y1);
        }
    }
}

// Kernel 1: streaming filter, x <= tau(L); survivors -> contiguous per-batch list.
__global__ __launch_bounds__(FTH) void filter_kernel(
    const float* __restrict__ corners, const int* __restrict__ lengths,
    u64* __restrict__ cand, uint32_t* __restrict__ gcount, int M, int NC)
{
    const int blk = blockIdx.x;
    const int b = blk / NC;
    const int q = blk - b * NC;
    const int tid = threadIdx.x;

    int L = lengths[b];
    if (L < 0) L = 0;
    if (L > M) L = M;
    const int start = q * CHUNK;
    int validq = L - start;
    if (validq <= 0) return;
    if (validq > CHUNK) validq = CHUNK;

    const float2* cp = (const float2*)corners + (size_t)b * M + start;
    u64* myc = cand + (size_t)b * CAP;

    if (L <= KEEPALL) {          // keep-all: unique slot = row index
        for (int i = tid; i < validq; i += FTH) {
            float2 c = cp[i];
            myc[start + i] = ((u64)fmap(c.x) << 32) | fmap(c.y);
        }
        if (tid == 0) atomicAdd(&gcount[b], (uint32_t)validq);
        return;
    }

    const float tau = norm_icdf(1.5f * (float)KOUT / (float)L) + 0.01f;
    const int lane = tid & 63;
    const float4* cp4 = (const float4*)cp;

    if (validq == CHUNK) {       // full chunk: unrolled hot path
        #pragma unroll
        for (int k = 0; k < CHUNK / 2 / FTH; ++k) {
            float4 v = cp4[tid + k * FTH];
            append_pair(myc, &gcount[b], lane, v.x <= tau, v.z <= tau,
                        v.x, v.y, v.z, v.w);
        }
    } else {                     // boundary chunk
        const int nv = validq >> 1;
        for (int i = tid; i < nv; i += FTH) {
            float4 v = cp4[i];
            append_pair(myc, &gcount[b], lane, v.x <= tau, v.z <= tau,
                        v.x, v.y, v.z, v.w);
        }
        if ((validq & 1) && tid == 0) {
            float2 c = cp[validq - 1];
            if (c.x <= tau) {
                uint32_t s = atomicAdd(&gcount[b], 1u);
                if (s < CAP) myc[s] = ((u64)fmap(c.x) << 32) | fmap(c.y);
            }
        }
    }
}

// Kernel 2: per batch: rank-select smallest Kb among candidates, write sorted.
__global__ __launch_bounds__(MTH) void merge_kernel(
    const float* __restrict__ corners, const int* __restrict__ lengths,
    const u64* __restrict__ cand, const uint32_t* __restrict__ gcount,
    float* __restrict__ out, int M)
{
    const int b = blockIdx.x;
    const int tid = threadIdx.x;
    int L = lengths[b];
    if (L < 0) L = 0;
    if (L > M) L = M;
    const int Kb = (L < KOUT) ? L : KOUT;
    float2* outb = (float2*)(out + (size_t)b * (2 * KOUT));

    for (int j = Kb + tid; j < KOUT; j += MTH)
        outb[j] = make_float2(0.0f, 0.0f);
    if (Kb == 0) return;

    __shared__ u64 cbuf[RBUF];
    __shared__ uint32_t hist[RNB];
    __shared__ uint32_t shT, shcnt;

    uint32_t n = gcount[b];
    const u64* myc = cand + (size_t)b * CAP;

    if (n >= (uint32_t)Kb && n <= CAP) {
        // ---- normal path: load candidates, direct O(n^2) rank-select ----
        for (uint32_t i = tid; i < n; i += MTH) cbuf[i] = myc[i];
        __syncthreads();
        for (uint32_t i = tid; i < n; i += MTH) {
            u64 ki = cbuf[i];
            uint32_t r = 0;
            for (uint32_t j = 0; j < n; ++j) {
                u64 kj = cbuf[j];
                r += (kj < ki) || (kj == ki && j < i);
            }
            if (r < (uint32_t)Kb)
                outb[r] = make_float2(funmap((uint32_t)(ki >> 32)), funmap((uint32_t)ki));
        }
        return;
    }

    // ---- exact fallback (statistically unreachable): histogram select ----
    for (int i = tid; i < RNB; i += MTH) hist[i] = 0u;
    if (tid == 0) { shT = RNB - 1; shcnt = 0u; }
    __syncthreads();
    const float2* cp = (const float2*)corners + (size_t)b * M;
    for (int i = tid; i < L; i += MTH)
        atomicAdd(&hist[fmap(cp[i].x) >> 20], 1u);
    __syncthreads();
    if (tid == 0) {
        uint32_t run = 0;
        for (int g = 0; g < RNB; ++g) {
            run += hist[g];
            if (run >= (uint32_t)Kb) { shT = (uint32_t)g; break; }
        }
    }
    __syncthreads();
    const uint32_t T = shT;
    for (int i = tid; i < L; i += MTH) {
        float2 c = cp[i];
        uint32_t kx = fmap(c.x);
        if ((kx >> 20) <= T) {
            uint32_t p = atomicAdd(&shcnt, 1u);
            if (p < RBUF) cbuf[p] = ((u64)kx << 32) | fmap(c.y);
        }
    }
    __syncthreads();
    int nn = (int)((shcnt < RBUF) ? shcnt : RBUF);
    for (int i = tid; i < nn; i += MTH) {
        u64 ki = cbuf[i];
        uint32_t r = 0;
        for (int j = 0; j < nn; ++j) {
            u64 kj = cbuf[j];
            r += (kj < ki) || (kj == ki && j < i);
        }
        if (r < (uint32_t)Kb)
            outb[r] = make_float2(funmap((uint32_t)(ki >> 32)), funmap((uint32_t)ki));
    }
}

extern "C" void kernel_launch(void* const* d_in, const int* in_sizes, int n_in,
                              void* d_out, int out_size, void* d_ws, size_t ws_size,
                              hipStream_t stream) {
    const float* corners = (const float*)d_in[0];
    const int* lengths   = (const int*)d_in[1];
    float* out = (float*)d_out;
    const int B = in_sizes[1];
    const int M = in_sizes[0] / (B * 2);
    const int NC = (M + CHUNK - 1) / CHUNK;   // 8 for M=32768

    u64* cand = (u64*)d_ws;
    uint32_t* gcount = (uint32_t*)((char*)d_ws + (size_t)B * CAP * sizeof(u64));

    hipMemsetAsync(gcount, 0, (size_t)B * sizeof(uint32_t), stream);
    filter_kernel<<<B * NC, FTH, 0, stream>>>(corners, lengths, cand, gcount, M, NC);
    merge_kernel<<<B, MTH, 0, stream>>>(corners, lengths, cand, gcount, out, M);
}

// Round 6
// 93.629 us; speedup vs baseline: 1.5723x; 1.5723x over previous
//
#include <hip/hip_runtime.h>
#include <stdint.h>
#include <math.h>

typedef unsigned long long u64;

#define KOUT    512
#define CHUNK   4096    // rows per filter block
#define FTH     256     // filter threads
#define SLOT    1280    // key slots per chunk (expected max ~768, +20 sigma)
#define KEEPALL 768     // L <= this: keep every valid row, no filtering
#define MTH     512     // merge threads
#define CBUF    2560    // merge candidate buffer (expected 768, +65 sigma)
#define RNB     4096    // fallback histogram bins

// Monotone float->uint32 map (order-preserving), exactly invertible.
__device__ __forceinline__ uint32_t fmap(float f) {
    uint32_t u = __float_as_uint(f);
    return (u & 0x80000000u) ? ~u : (u | 0x80000000u);
}
__device__ __forceinline__ float funmap(uint32_t m) {
    uint32_t u = (m & 0x80000000u) ? (m & 0x7fffffffu) : ~m;
    return __uint_as_float(u);
}
__device__ __forceinline__ u64 pack(float x, float y) {
    return ((u64)fmap(x) << 32) | fmap(y);
}

// Acklam inverse normal CDF (float); ~1e-3 accuracy, exactness verified downstream.
__device__ __forceinline__ float norm_icdf(float p) {
    const float a1=-3.969683028665376e+01f,a2= 2.209460984245205e+02f,a3=-2.759285104469687e+02f,
                a4= 1.383577518672690e+02f,a5=-3.066479806614716e+01f,a6= 2.506628277459239e+00f;
    const float b1=-5.447609879822406e+01f,b2= 1.615858368580409e+02f,b3=-1.556989798598866e+02f,
                b4= 6.680131188771972e+01f,b5=-1.328068155288572e+01f;
    const float c1=-7.784894002430293e-03f,c2=-3.223964580411365e-01f,c3=-2.400758277161838e+00f,
                c4=-2.549732539343734e+00f,c5= 4.374664141464968e+00f,c6= 2.938163982698783e+00f;
    const float d1= 7.784695709041462e-03f,d2= 3.224671290700398e-01f,d3= 2.445134137142996e+00f,
                d4= 3.754408661907416e+00f;
    if (p < 0.02425f) {
        float q = sqrtf(-2.0f * logf(p));
        return (((((c1*q+c2)*q+c3)*q+c4)*q+c5)*q+c6) / ((((d1*q+d2)*q+d3)*q+d4)*q+1.0f);
    } else if (p <= 0.97575f) {
        float q = p - 0.5f, r = q*q;
        return (((((a1*r+a2)*r+a3)*r+a4)*r+a5)*r+a6)*q / (((((b1*r+b2)*r+b3)*r+b4)*r+b5)*r+1.0f);
    } else {
        float q = sqrtf(-2.0f * logf(1.0f - p));
        return -(((((c1*q+c2)*q+c3)*q+c4)*q+c5)*q+c6) / ((((d1*q+d2)*q+d3)*q+d4)*q+1.0f);
    }
}

// Kernel 1: streaming filter. Survivors (x <= tau(L)) -> per-chunk slot region,
// slots assigned via LDS counter (one LDS atomic per wave-iter). Counts written
// unconditionally (raw, so overflow is detectable downstream).
__global__ __launch_bounds__(FTH) void filter_kernel(
    const float* __restrict__ corners, const int* __restrict__ lengths,
    u64* __restrict__ keys, uint32_t* __restrict__ counts, int M, int NC)
{
    const int blk = blockIdx.x;
    const int b = blk / NC;
    const int q = blk - b * NC;
    const int tid = threadIdx.x;

    int L = lengths[b];
    if (L < 0) L = 0;
    if (L > M) L = M;
    const int start = q * CHUNK;
    int validq = L - start;
    if (validq <= 0) { if (tid == 0) counts[blk] = 0u; return; }
    if (validq > CHUNK) validq = CHUNK;

    const float2* cp = (const float2*)corners + (size_t)b * M + start;
    u64* myk = keys + (size_t)blk * SLOT;

    if (L <= KEEPALL) {             // keep-all: slot = local row index
        for (int i = tid; i < validq; i += FTH)
            myk[i] = pack(cp[i].x, cp[i].y);
        if (tid == 0) counts[blk] = (uint32_t)validq;
        return;
    }

    __shared__ uint32_t shcnt;
    if (tid == 0) shcnt = 0u;
    __syncthreads();

    const float tau = norm_icdf(1.5f * (float)KOUT / (float)L) + 0.01f;
    const int lane = tid & 63;
    const float4* cp4 = (const float4*)cp;
    const int nv = validq >> 1;

    for (int i = tid; i < nv; i += FTH) {
        float4 v = cp4[i];
        bool k0 = (v.x <= tau), k1 = (v.z <= tau);
        u64 m0 = __ballot(k0), m1 = __ballot(k1);
        if (m0 | m1) {
            int c0 = __popcll(m0);
            int ct = c0 + __popcll(m1);
            uint32_t base = 0;
            if (lane == 0) base = atomicAdd(&shcnt, (uint32_t)ct);
            base = __shfl(base, 0, 64);
            u64 lt = ((u64)1 << lane) - 1ull;
            if (k0) {
                uint32_t s = base + (uint32_t)__popcll(m0 & lt);
                if (s < SLOT) myk[s] = pack(v.x, v.y);
            }
            if (k1) {
                uint32_t s = base + (uint32_t)(c0 + __popcll(m1 & lt));
                if (s < SLOT) myk[s] = pack(v.z, v.w);
            }
        }
    }
    if ((validq & 1) && tid == 0) {
        float2 c = cp[validq - 1];
        if (c.x <= tau) {
            uint32_t s = atomicAdd(&shcnt, 1u);
            if (s < SLOT) myk[s] = pack(c.x, c.y);
        }
    }
    __syncthreads();
    if (tid == 0) counts[blk] = shcnt;   // raw (may exceed SLOT -> fallback)
}

// Kernel 2: per batch: gather survivors into LDS, O(n^2) rank-select, write
// sorted + zero-pad. Exact in-kernel fallback if guards trip (never, in practice).
__global__ __launch_bounds__(MTH) void merge_kernel(
    const float* __restrict__ corners, const int* __restrict__ lengths,
    const u64* __restrict__ keys, const uint32_t* __restrict__ counts,
    float* __restrict__ out, int M, int NC)
{
    const int b = blockIdx.x;
    const int tid = threadIdx.x;
    int L = lengths[b];
    if (L < 0) L = 0;
    if (L > M) L = M;
    const int Kb = (L < KOUT) ? L : KOUT;
    float2* outb = (float2*)(out + (size_t)b * (2 * KOUT));

    for (int j = Kb + tid; j < KOUT; j += MTH)
        outb[j] = make_float2(0.0f, 0.0f);
    if (Kb == 0) return;

    __shared__ u64 cbuf[CBUF];           // 20 KB
    __shared__ uint32_t hist[RNB];       // 16 KB (fallback only)
    __shared__ uint32_t shT, shcnt;

    uint32_t n = 0, bad = 0;
    for (int q = 0; q < NC; ++q) {
        uint32_t c = counts[b * NC + q];
        if (c > SLOT) bad = 1u;
        n += (c > SLOT) ? SLOT : c;
    }

    if (!bad && n >= (uint32_t)Kb && n <= CBUF) {
        // ---- normal path ----
        uint32_t off = 0;
        for (int q = 0; q < NC; ++q) {
            uint32_t c = counts[b * NC + q];
            const u64* src = keys + (size_t)(b * NC + q) * SLOT;
            for (uint32_t i = tid; i < c; i += MTH) cbuf[off + i] = src[i];
            off += c;
        }
        __syncthreads();
        for (uint32_t i = tid; i < n; i += MTH) {
            u64 ki = cbuf[i];
            uint32_t r = 0;
            for (uint32_t j = 0; j < n; ++j) {
                u64 kj = cbuf[j];
                r += (kj < ki) || (kj == ki && j < i);
            }
            if (r < (uint32_t)Kb)
                outb[r] = make_float2(funmap((uint32_t)(ki >> 32)), funmap((uint32_t)ki));
        }
        return;
    }

    // ---- exact fallback: histogram select over the raw rows ----
    for (int i = tid; i < RNB; i += MTH) hist[i] = 0u;
    if (tid == 0) { shT = RNB - 1; shcnt = 0u; }
    __syncthreads();
    const float2* cp = (const float2*)corners + (size_t)b * M;
    for (int i = tid; i < L; i += MTH)
        atomicAdd(&hist[fmap(cp[i].x) >> 20], 1u);
    __syncthreads();
    if (tid == 0) {
        uint32_t run = 0;
        for (int g = 0; g < RNB; ++g) {
            run += hist[g];
            if (run >= (uint32_t)Kb) { shT = (uint32_t)g; break; }
        }
    }
    __syncthreads();
    const uint32_t T = shT;
    for (int i = tid; i < L; i += MTH) {
        float2 c = cp[i];
        uint32_t kx = fmap(c.x);
        if ((kx >> 20) <= T) {
            uint32_t p = atomicAdd(&shcnt, 1u);
            if (p < CBUF) cbuf[p] = ((u64)kx << 32) | fmap(c.y);
        }
    }
    __syncthreads();
    int nn = (int)((shcnt < CBUF) ? shcnt : CBUF);
    for (int i = tid; i < nn; i += MTH) {
        u64 ki = cbuf[i];
        uint32_t r = 0;
        for (int j = 0; j < nn; ++j) {
            u64 kj = cbuf[j];
            r += (kj < ki) || (kj == ki && j < i);
        }
        if (r < (uint32_t)Kb)
            outb[r] = make_float2(funmap((uint32_t)(ki >> 32)), funmap((uint32_t)ki));
    }
}

extern "C" void kernel_launch(void* const* d_in, const int* in_sizes, int n_in,
                              void* d_out, int out_size, void* d_ws, size_t ws_size,
                              hipStream_t stream) {
    const float* corners = (const float*)d_in[0];
    const int* lengths   = (const int*)d_in[1];
    float* out = (float*)d_out;
    const int B = in_sizes[1];
    const int M = in_sizes[0] / (B * 2);
    const int NC = (M + CHUNK - 1) / CHUNK;   // 8 for M=32768

    u64* keys = (u64*)d_ws;
    uint32_t* counts = (uint32_t*)((char*)d_ws + (size_t)B * NC * SLOT * sizeof(u64));

    filter_kernel<<<B * NC, FTH, 0, stream>>>(corners, lengths, keys, counts, M, NC);
    merge_kernel<<<B, MTH, 0, stream>>>(corners, lengths, keys, counts, out, M, NC);
}

// Round 7
// 28.308 us; speedup vs baseline: 5.2005x; 3.3075x over previous
//
#include <hip/hip_runtime.h>
#include <stdint.h>
#include <math.h>

typedef unsigned long long u64;

#define NT     1024
#define KOUT   512
#define DIRECT 1024     // L <= DIRECT: load rows directly, no filter
#define FNB    4096     // fallback histogram bins
#define FCAP   2048     // fallback candidate buffer

// Monotone float->uint32 map (order-preserving), exactly invertible.
__device__ __forceinline__ uint32_t fmap(float f) {
    uint32_t u = __float_as_uint(f);
    return (u & 0x80000000u) ? ~u : (u | 0x80000000u);
}
__device__ __forceinline__ float funmap(uint32_t m) {
    uint32_t u = (m & 0x80000000u) ? (m & 0x7fffffffu) : ~m;
    return __uint_as_float(u);
}
__device__ __forceinline__ u64 pack(float x, float y) {
    return ((u64)fmap(x) << 32) | (u64)fmap(y);
}
__device__ __forceinline__ u64 shfl_xor_u64(u64 v, int j) {
    uint32_t lo = __shfl_xor((uint32_t)v, j, 64);
    uint32_t hi = __shfl_xor((uint32_t)(v >> 32), j, 64);
    return ((u64)hi << 32) | lo;
}

// Acklam inverse normal CDF (float); ~1e-3 accuracy, exactness guarded downstream.
__device__ __forceinline__ float norm_icdf(float p) {
    const float a1=-3.969683028665376e+01f,a2= 2.209460984245205e+02f,a3=-2.759285104469687e+02f,
                a4= 1.383577518672690e+02f,a5=-3.066479806614716e+01f,a6= 2.506628277459239e+00f;
    const float b1=-5.447609879822406e+01f,b2= 1.615858368580409e+02f,b3=-1.556989798598866e+02f,
                b4= 6.680131188771972e+01f,b5=-1.328068155288572e+01f;
    const float c1=-7.784894002430293e-03f,c2=-3.223964580411365e-01f,c3=-2.400758277161838e+00f,
                c4=-2.549732539343734e+00f,c5= 4.374664141464968e+00f,c6= 2.938163982698783e+00f;
    const float d1= 7.784695709041462e-03f,d2= 3.224671290700398e-01f,d3= 2.445134137142996e+00f,
                d4= 3.754408661907416e+00f;
    if (p < 0.02425f) {
        float q = sqrtf(-2.0f * logf(p));
        return (((((c1*q+c2)*q+c3)*q+c4)*q+c5)*q+c6) / ((((d1*q+d2)*q+d3)*q+d4)*q+1.0f);
    } else if (p <= 0.97575f) {
        float q = p - 0.5f, r = q*q;
        return (((((a1*r+a2)*r+a3)*r+a4)*r+a5)*r+a6)*q / (((((b1*r+b2)*r+b3)*r+b4)*r+b5)*r+1.0f);
    } else {
        float q = sqrtf(-2.0f * logf(1.0f - p));
        return -(((((c1*q+c2)*q+c3)*q+c4)*q+c5)*q+c6) / ((((d1*q+d2)*q+d3)*q+d4)*q+1.0f);
    }
}

__global__ __launch_bounds__(NT) void topk_kernel(
    const float* __restrict__ corners, const int* __restrict__ lengths,
    float* __restrict__ out, int M)
{
    const int b = blockIdx.x;
    const int tid = threadIdx.x;
    int L = lengths[b];
    if (L < 0) L = 0;
    if (L > M) L = M;
    const int Kb = (L < KOUT) ? L : KOUT;
    float2* outb = (float2*)(out + (size_t)b * (2 * KOUT));

    if (L == 0) {
        if (tid < KOUT) outb[tid] = make_float2(0.0f, 0.0f);
        return;
    }

    __shared__ u64 sbuf[NT];         // candidate buffer, then bitonic exchange
    __shared__ uint32_t shcnt;
    __shared__ uint32_t shT;
    __shared__ uint32_t hist[FNB];   // fallback only
    __shared__ u64 fcand[FCAP];      // fallback only

    const float2* cp = (const float2*)corners + (size_t)b * M;

    u64 key = ~0ull;
    uint32_t n;
    bool fb = false;

    if (L <= DIRECT) {
        // ---- direct path: every valid row is a candidate ----
        n = (uint32_t)L;
        if (tid < L) { float2 c = cp[tid]; key = pack(c.x, c.y); }
    } else {
        // ---- filtered path: keep x <= tau(L), expected n ~ 768 +- 28 ----
        if (tid == 0) shcnt = 0u;
        __syncthreads();
        const float tau = norm_icdf(768.0f / (float)L) + 0.01f;
        const int lane = tid & 63;
        const float4* cp4 = (const float4*)cp;
        const int nv = L >> 1;

        for (int i = tid; i < nv; i += NT) {
            float4 v = cp4[i];
            bool k0 = (v.x <= tau), k1 = (v.z <= tau);
            u64 m0 = __ballot(k0), m1 = __ballot(k1);
            if (m0 | m1) {
                int c0 = __popcll(m0);
                uint32_t base = 0;
                if (lane == 0) base = atomicAdd(&shcnt, (uint32_t)(c0 + __popcll(m1)));
                base = __shfl(base, 0, 64);
                u64 lt = ((u64)1 << lane) - 1ull;
                if (k0) {
                    uint32_t s = base + (uint32_t)__popcll(m0 & lt);
                    if (s < NT) sbuf[s] = pack(v.x, v.y);
                }
                if (k1) {
                    uint32_t s = base + (uint32_t)(c0 + __popcll(m1 & lt));
                    if (s < NT) sbuf[s] = pack(v.z, v.w);
                }
            }
        }
        if ((L & 1) && tid == 0) {
            float2 c = cp[L - 1];
            if (c.x <= tau) {
                uint32_t s = atomicAdd(&shcnt, 1u);
                if (s < NT) sbuf[s] = pack(c.x, c.y);
            }
        }
        __syncthreads();
        n = shcnt;
        if (n < (uint32_t)Kb || n > NT) fb = true;   // block-uniform
        else if (tid < n) key = sbuf[tid];
    }

    if (!fb) {
        __syncthreads();   // all sbuf reads complete before sort reuses it
        // ---- bitonic sort of 1024 keys, one per thread, ascending ----
        for (uint32_t k = 2; k <= NT; k <<= 1) {
            uint32_t j = k >> 1;
            for (; j >= 64; j >>= 1) {          // cross-wave: LDS exchange
                sbuf[tid] = key;
                __syncthreads();
                u64 pk = sbuf[tid ^ j];
                __syncthreads();
                bool lower = ((tid & j) == 0);
                bool wantmin = (((tid & k) == 0) == lower);
                key = ((pk < key) == wantmin) ? pk : key;
            }
            for (; j > 0; j >>= 1) {            // in-wave: shuffle exchange
                u64 pk = shfl_xor_u64(key, (int)j);
                bool lower = ((tid & j) == 0);
                bool wantmin = (((tid & k) == 0) == lower);
                key = ((pk < key) == wantmin) ? pk : key;
            }
        }
        // thread t holds the t-th smallest key
        if (tid < KOUT) {
            float2 o = make_float2(0.0f, 0.0f);
            if (tid < Kb) {
                o.x = funmap((uint32_t)(key >> 32));
                o.y = funmap((uint32_t)key);
            }
            outb[tid] = o;
        }
        return;
    }

    // ---- exact fallback (statistically unreachable; guards verified) ----
    if (tid == 0) { shcnt = 0u; shT = FNB - 1; }
    for (int i = tid; i < FNB; i += NT) hist[i] = 0u;
    __syncthreads();
    for (int i = tid; i < L; i += NT)
        atomicAdd(&hist[fmap(cp[i].x) >> 20], 1u);
    __syncthreads();
    if (tid == 0) {
        uint32_t run = 0;
        for (int g = 0; g < FNB; ++g) {
            run += hist[g];
            if (run >= (uint32_t)Kb) { shT = (uint32_t)g; break; }
        }
    }
    __syncthreads();
    const uint32_t T = shT;
    for (int i = tid; i < L; i += NT) {
        float2 c = cp[i];
        uint32_t kx = fmap(c.x);
        if ((kx >> 20) <= T) {
            uint32_t p = atomicAdd(&shcnt, 1u);
            if (p < FCAP) fcand[p] = ((u64)kx << 32) | fmap(c.y);
        }
    }
    __syncthreads();
    const int nn = (int)((shcnt < FCAP) ? shcnt : FCAP);
    for (int jj = Kb + tid; jj < KOUT; jj += NT)
        outb[jj] = make_float2(0.0f, 0.0f);
    for (int i = tid; i < nn; i += NT) {
        u64 ki = fcand[i];
        uint32_t r = 0;
        for (int jj = 0; jj < nn; ++jj) {
            u64 kj = fcand[jj];
            r += (kj < ki) || (kj == ki && jj < i);
        }
        if (r < (uint32_t)Kb)
            outb[r] = make_float2(funmap((uint32_t)(ki >> 32)), funmap((uint32_t)ki));
    }
}

extern "C" void kernel_launch(void* const* d_in, const int* in_sizes, int n_in,
                              void* d_out, int out_size, void* d_ws, size_t ws_size,
                              hipStream_t stream) {
    const float* corners = (const float*)d_in[0];
    const int* lengths   = (const int*)d_in[1];
    float* out = (float*)d_out;
    const int B = in_sizes[1];
    const int M = in_sizes[0] / (B * 2);
    topk_kernel<<<B, NT, 0, stream>>>(corners, lengths, out, M);
}